// Round 15
// baseline (676.738 us; speedup 1.0000x reference)
//
#include <hip/hip_runtime.h>
#include <hip/hip_cooperative_groups.h>
#include <hip/hip_bf16.h>
#include <math.h>

namespace cg = cooperative_groups;

// Problem constants
#define CDIM  128
#define NCODE 16384
#define ELEMS 524288         // B*C*J*L
#define NTOT  5456           // 16+64+256+1024+4096
#define WEXT_TOT 589824      // 4*128*1152
// loss coeff: 1.25 / (5 * 524288) == 2^-21
#define LOSS_COEF 4.76837158203125e-7f

typedef __attribute__((ext_vector_type(8))) short short8;
typedef __attribute__((ext_vector_type(4))) float float4v;
typedef unsigned short ushortT;
typedef unsigned long long u64;
typedef unsigned int u32;

__device__ __forceinline__ ushortT f2bf(float x) {
    __hip_bfloat16 h = __float2bfloat16(x);
    return *reinterpret_cast<ushortT*>(&h);
}
__device__ __forceinline__ float bf2f(ushortT b) {
    __hip_bfloat16 h = *reinterpret_cast<__hip_bfloat16*>(&b);
    return __bfloat162float(h);
}
__device__ __forceinline__ u32 ford(float v) {
    u32 b = __float_as_uint(v);
    return b ^ ((u32)((int)b >> 31) | 0x80000000u);
}
__device__ double cubic_d(double x) {
    const double a = -0.75;
    double ax = fabs(x);
    if (ax <= 1.0) return (a + 2.0) * ax * ax * ax - (a + 3.0) * ax * ax + 1.0;
    if (ax < 2.0)  return a * ax * ax * ax - 5.0 * a * ax * ax + 8.0 * a * ax - 4.0 * a;
    return 0.0;
}

// ===========================================================================
// Shared device bodies
// ===========================================================================

// argmin job body, SINGLE-buffer TC=64 (32 KB smem), 2 barriers/tile (R3
// config, 54.8us @ scale4) — fits coop occupancy. XCD-pinned ky = jid % KS.
__device__ __forceinline__
void dev_argmin_sb(char* smem, int jid, const ushortT* __restrict__ rext,
                   const ushortT* __restrict__ embext, const float* __restrict__ esq,
                   int N, int kPerSplit, int KS, u64* __restrict__ packed, int t) {
    ushortT* B0 = reinterpret_cast<ushortT*>(smem);      // 32 KB
    const int w = t >> 6;
    const int lane = t & 63;
    const int ln = lane & 15;
    const int q  = lane >> 4;
    const int ky = jid % KS;
    const int rb = jid / KS;
    const int k0beg = ky * kPerSplit;
    const int rowW = rb * 128 + w * 32;

    short8 a[2][8];
    #pragma unroll
    for (int ti = 0; ti < 2; ++ti) {
        const ushortT* r0 = rext + (size_t)(rowW + ti * 16 + ln) * 256 + q * 8;
        #pragma unroll
        for (int sb = 0; sb < 8; ++sb)
            a[ti][sb] = *reinterpret_cast<const short8*>(r0 + sb * 32);
    }

    float minv[2][4];
    int   mini[2][4];
    #pragma unroll
    for (int ti = 0; ti < 2; ++ti)
        #pragma unroll
        for (int rg = 0; rg < 4; ++rg) { minv[ti][rg] = 3.4e38f; mini[ti][rg] = 0; }

    const int tiles = kPerSplit >> 6;
    for (int it = 0; it < tiles; ++it) {
        __syncthreads();                       // prev tile fully consumed
        int k0 = k0beg + it * 64;
        #pragma unroll
        for (int i = 0; i < 8; ++i) {
            int F = (i * 4 + w) * 64 + lane;
            int n = F >> 5, cs = F & 31;
            int cp = (cs & ~7) | ((cs & 7) ^ (n & 7));
            const ushortT* src = embext + (size_t)(k0 + n) * 256 + cp * 8;
            __builtin_amdgcn_global_load_lds(
                (const __attribute__((address_space(1))) unsigned int*)src,
                (__attribute__((address_space(3))) unsigned int*)&B0[(size_t)((i * 4 + w) * 64) * 8],
                16, 0, 0);
        }
        __syncthreads();                       // staging visible

        #pragma unroll
        for (int sub = 0; sub < 4; ++sub) {
            int n = sub * 16 + ln;
            short8 bfr[8];
            #pragma unroll
            for (int sb = 0; sb < 8; ++sb) {
                int cp = q + 4 * sb;
                int cs = (cp & ~7) | ((cp & 7) ^ (n & 7));
                bfr[sb] = *reinterpret_cast<const short8*>(&B0[(size_t)(n * 32 + cs) * 8]);
            }
            float4v acc[2];
            #pragma unroll
            for (int ti = 0; ti < 2; ++ti) acc[ti] = (float4v){0.f, 0.f, 0.f, 0.f};
            #pragma unroll
            for (int s = 0; s < 12; ++s) {
                int as = s < 8 ? s : s - 8;
                int bs = s < 4 ? s : s - 4;
                #pragma unroll
                for (int ti = 0; ti < 2; ++ti)
                    acc[ti] = __builtin_amdgcn_mfma_f32_16x16x32_bf16(a[ti][as], bfr[bs], acc[ti], 0, 0, 0);
            }
            int kc = k0 + sub * 16 + ln;
            float es = esq[kc];
            #pragma unroll
            for (int ti = 0; ti < 2; ++ti)
                #pragma unroll
                for (int rg = 0; rg < 4; ++rg) {
                    float sc = fmaf(-2.f, acc[ti][rg], es);
                    if (sc < minv[ti][rg]) { minv[ti][rg] = sc; mini[ti][rg] = kc; }
                }
        }
    }

    #pragma unroll
    for (int ti = 0; ti < 2; ++ti)
        #pragma unroll
        for (int rg = 0; rg < 4; ++rg) {
            float v = minv[ti][rg]; int ix = mini[ti][rg];
            #pragma unroll
            for (int off = 1; off < 16; off <<= 1) {
                float ov = __shfl_xor(v, off);
                int   oi = __shfl_xor(ix, off);
                if (ov < v || (ov == v && oi < ix)) { v = ov; ix = oi; }
            }
            if (ln == 0) {
                int row = rowW + ti * 16 + q * 4 + rg;
                if (row < N) {
                    u64 p = ((u64)ford(v) << 32) | (u32)ix;
                    atomicMin(&packed[row], p);
                }
            }
        }
}

// upconv job body (R11-verbatim): separable bicubic + MFMA conv + epilogue.
__device__ __forceinline__
void dev_upconv(char* smem, int job, const float* __restrict__ emb,
                const u64* __restrict__ packed, const float* __restrict__ wm,
                int S, int lastScale, const ushortT* __restrict__ wext,
                const float* __restrict__ bias, const float* __restrict__ f_in,
                float* __restrict__ f_hat, float* __restrict__ f_rest,
                float* __restrict__ loss_acc, int storeRest, int packNext,
                ushortT* __restrict__ rext_out, int t) {
    ushortT* Htile = reinterpret_cast<ushortT*>(smem);           // 12 KB
    float*   tmpS  = reinterpret_cast<float*>(smem + 12288);     // 12 KB
    float*   wsum  = reinterpret_cast<float*>(smem + 24576);     // 16 B
    const int b = job >> 4;
    const int j = job & 15;
    const int l = t >> 4, c8 = t & 15;
    const int phys = (c8 & 8) | ((c8 & 7) ^ (l & 7));

    if (lastScale) {
        #pragma unroll
        for (int r = 0; r < 3; ++r) {
            int jin = j - 1 + r;
            float acc[8] = {0.f, 0.f, 0.f, 0.f, 0.f, 0.f, 0.f, 0.f};
            if (jin >= 0 && jin < 16) {
                int idx = (int)(u32)(packed[(b * 16 + jin) * 16 + l] & 0xFFFFFFFFull);
                const float* er = emb + (size_t)idx * CDIM + c8 * 8;
                float4 e0 = *reinterpret_cast<const float4*>(er);
                float4 e1 = *reinterpret_cast<const float4*>(er + 4);
                acc[0] = e0.x; acc[1] = e0.y; acc[2] = e0.z; acc[3] = e0.w;
                acc[4] = e1.x; acc[5] = e1.y; acc[6] = e1.z; acc[7] = e1.w;
            }
            short8 o;
            #pragma unroll
            for (int i = 0; i < 8; ++i) o[i] = (short)f2bf(acc[i]);
            *reinterpret_cast<short8*>(&Htile[((size_t)(r * 16 + l) * 16 + phys) * 8]) = o;
        }
    } else {
        int items = 3 * S * 16;
        for (int i = t; i < items; i += 256) {
            int r = i / (S * 16);
            int rem = i - r * (S * 16);
            int t2 = rem >> 4, cc8 = rem & 15;
            int jin = j - 1 + r;
            float a0[8] = {0.f, 0.f, 0.f, 0.f, 0.f, 0.f, 0.f, 0.f};
            if (jin >= 0 && jin < 16) {
                for (int s = 0; s < S; ++s) {
                    float wjv = wm[jin * S + s];
                    int idx = (int)(u32)(packed[b * S * S + s * S + t2] & 0xFFFFFFFFull);
                    const float* er = emb + (size_t)idx * CDIM + cc8 * 8;
                    float4 e0 = *reinterpret_cast<const float4*>(er);
                    float4 e1 = *reinterpret_cast<const float4*>(er + 4);
                    a0[0] += wjv * e0.x; a0[1] += wjv * e0.y;
                    a0[2] += wjv * e0.z; a0[3] += wjv * e0.w;
                    a0[4] += wjv * e1.x; a0[5] += wjv * e1.y;
                    a0[6] += wjv * e1.z; a0[7] += wjv * e1.w;
                }
            }
            float* tp = &tmpS[((size_t)(r * 8 + t2)) * 128 + cc8 * 8];
            *reinterpret_cast<float4*>(tp)     = make_float4(a0[0], a0[1], a0[2], a0[3]);
            *reinterpret_cast<float4*>(tp + 4) = make_float4(a0[4], a0[5], a0[6], a0[7]);
        }
        __syncthreads();
        #pragma unroll
        for (int r = 0; r < 3; ++r) {
            float acc[8] = {0.f, 0.f, 0.f, 0.f, 0.f, 0.f, 0.f, 0.f};
            for (int t2 = 0; t2 < S; ++t2) {
                float wlv = wm[l * S + t2];
                const float* tp = &tmpS[((size_t)(r * 8 + t2)) * 128 + c8 * 8];
                float4 v0 = *reinterpret_cast<const float4*>(tp);
                float4 v1 = *reinterpret_cast<const float4*>(tp + 4);
                acc[0] += wlv * v0.x; acc[1] += wlv * v0.y;
                acc[2] += wlv * v0.z; acc[3] += wlv * v0.w;
                acc[4] += wlv * v1.x; acc[5] += wlv * v1.y;
                acc[6] += wlv * v1.z; acc[7] += wlv * v1.w;
            }
            short8 o;
            #pragma unroll
            for (int i = 0; i < 8; ++i) o[i] = (short)f2bf(acc[i]);
            *reinterpret_cast<short8*>(&Htile[((size_t)(r * 16 + l) * 16 + phys) * 8]) = o;
        }
    }
    __syncthreads();

    const int w = t >> 6, lane = t & 63;
    const int ln = lane & 15, q = lane >> 4;
    const int co0 = w * 32;
    const ushortT* wA = wext + (size_t)(co0 + ln) * 1152;
    float4v acc2[2] = {{0.f, 0.f, 0.f, 0.f}, {0.f, 0.f, 0.f, 0.f}};
    const short8 zz = {0, 0, 0, 0, 0, 0, 0, 0};

    #pragma unroll 3
    for (int off = 0; off < 9; ++off) {
        const int dj = off / 3, dl = off % 3;
        int cIn = ln + dl - 1;
        int cCl = cIn < 0 ? 0 : (cIn > 15 ? 15 : cIn);
        bool oob = (cIn != cCl);
        int rb = (dj * 16 + cCl) * 128;
        #pragma unroll
        for (int g = 0; g < 4; ++g) {
            int csl = g * 4 + q;
            int ph2 = (csl & 8) | ((csl & 7) ^ (cCl & 7));
            short8 av = *reinterpret_cast<const short8*>(&Htile[rb + ph2 * 8]);
            if (oob) av = zz;
            const ushortT* wr = wA + (off * 4 + g) * 32 + q * 8;
            short8 b0 = *reinterpret_cast<const short8*>(wr);
            short8 b1 = *reinterpret_cast<const short8*>(wr + 16 * 1152);
            acc2[0] = __builtin_amdgcn_mfma_f32_16x16x32_bf16(av, b0, acc2[0], 0, 0, 0);
            acc2[1] = __builtin_amdgcn_mfma_f32_16x16x32_bf16(av, b1, acc2[1], 0, 0, 0);
        }
    }

    float s = 0.f;
    #pragma unroll
    for (int sn = 0; sn < 2; ++sn) {
        int co = co0 + sn * 16 + ln;
        float bsv = 0.5f * bias[co];
        size_t gi = ((size_t)(b * 128 + co) * 16 + j) * 16 + q * 4;
        float4 fh = *reinterpret_cast<const float4*>(&f_hat[gi]);
        float4 fv = *reinterpret_cast<const float4*>(&f_in[gi]);
        float oo[4] = {acc2[sn][0] + bsv, acc2[sn][1] + bsv,
                       acc2[sn][2] + bsv, acc2[sn][3] + bsv};
        float fhv[4] = {fh.x + oo[0], fh.y + oo[1], fh.z + oo[2], fh.w + oo[3]};
        *reinterpret_cast<float4*>(&f_hat[gi]) =
            make_float4(fhv[0], fhv[1], fhv[2], fhv[3]);
        float fvv[4] = {fv.x, fv.y, fv.z, fv.w};
        #pragma unroll
        for (int i = 0; i < 4; ++i) {
            float d = fhv[i] - fvv[i];
            s += d * d;
        }
        if (storeRest || packNext) {
            float4 fr = *reinterpret_cast<const float4*>(&f_rest[gi]);
            float frn[4] = {fr.x - oo[0], fr.y - oo[1], fr.z - oo[2], fr.w - oo[3]};
            if (storeRest)
                *reinterpret_cast<float4*>(&f_rest[gi]) =
                    make_float4(frn[0], frn[1], frn[2], frn[3]);
            if (packNext) {
                #pragma unroll
                for (int i = 0; i < 4; ++i) {
                    int row = b * 256 + j * 16 + q * 4 + i;
                    ushortT hv = f2bf(frn[i]);
                    rext_out[(size_t)row * 256 + co] = hv;
                    rext_out[(size_t)row * 256 + 128 + co] = f2bf(frn[i] - bf2f(hv));
                }
            }
        }
    }
    #pragma unroll
    for (int off = 32; off; off >>= 1) s += __shfl_down(s, off);
    if (lane == 0) wsum[w] = s;
    __syncthreads();
    if (t == 0)
        atomicAdd(loss_acc, (wsum[0] + wsum[1] + wsum[2] + wsum[3]) * LOSS_COEF);
}

// ===========================================================================
// Mega-kernel (cooperative): whole pipeline, 32 KB LDS, job-strided phases
// so ANY grid size is correct; grid sized by occupancy query at launch.
// ===========================================================================
__global__ __launch_bounds__(256, 2)
void k_mega(const float* __restrict__ f, const float* __restrict__ emb,
            const float* __restrict__ phi_w, const float* __restrict__ phi_b,
            float* __restrict__ out, float* __restrict__ f_rest,
            float* __restrict__ esq, float* __restrict__ wmat,
            float* __restrict__ lossA, u64* __restrict__ packed,
            ushortT* __restrict__ embext, ushortT* __restrict__ rext,
            ushortT* __restrict__ wext) {
    cg::grid_group grid = cg::this_grid();
    __shared__ __align__(16) char smem[32768];
    const int t = threadIdx.x;
    const int bid = blockIdx.x;
    const int NB = gridDim.x;

    // ---------------- prologue ----------------
    {
        float* red = reinterpret_cast<float*>(smem);
        for (int base = bid * 256; base < WEXT_TOT; base += NB * 256) {
            int id = base + t;
            if (base < ELEMS) {
                float fv = f[id];
                f_rest[id] = fv;
                out[id] = 0.f;                     // f_hat
                int row = id >> 5, c4 = id & 31;
                float4 v = reinterpret_cast<const float4*>(emb + (size_t)row * CDIM)[c4];
                float xs[4] = {v.x, v.y, v.z, v.w};
                ushortT hi[4], lo[4];
                float ss = 0.f;
                #pragma unroll
                for (int i = 0; i < 4; ++i) {
                    hi[i] = f2bf(xs[i]);
                    lo[i] = f2bf(xs[i] - bf2f(hi[i]));
                    ss += xs[i] * xs[i];
                }
                ushortT* basep = embext + (size_t)row * 256;
                *reinterpret_cast<ushort4*>(basep + c4 * 4)       = make_ushort4(hi[0], hi[1], hi[2], hi[3]);
                *reinterpret_cast<ushort4*>(basep + 128 + c4 * 4) = make_ushort4(lo[0], lo[1], lo[2], lo[3]);
                #pragma unroll
                for (int off = 16; off; off >>= 1) ss += __shfl_down(ss, off);
                if ((t & 31) == 0) esq[row] = ss;

                // scale-0 pack: plane mean (this iteration == one (b,c) plane)
                float s = fv;
                #pragma unroll
                for (int off = 32; off; off >>= 1) s += __shfl_down(s, off);
                if ((t & 63) == 0) red[t >> 6] = s;
                __syncthreads();
                if (t == 0) {
                    float m = (red[0] + red[1] + red[2] + red[3]) * (1.f / 256.f);
                    int plane = base >> 8;
                    int b = plane >> 7, c = plane & 127;
                    ushortT h = f2bf(m);
                    rext[b * 256 + c] = h;
                    rext[b * 256 + 128 + c] = f2bf(m - bf2f(h));
                }
                __syncthreads();
            }
            if (id < WEXT_TOT) {
                int k4 = id / 147456, rem = id % 147456;
                int co = rem / 1152, kk = rem % 1152;
                int off = kk >> 7, ci = kk & 127;
                float v = 0.5f * phi_w[(((size_t)(k4 * 128 + co)) * 128 + ci) * 9 + off];
                if (ci == co && off == 4) v += 0.5f;
                wext[id] = f2bf(v);
            }
        }
        for (int idz = bid * 256 + t; idz < 30720; idz += NB * 256)
            reinterpret_cast<u32*>(rext + 16 * 256)[idz] = 0;   // rext pad rows
        if (bid == 0 && t < 64) {
            int sIdx = t >> 4;
            int S = 1 << sIdx;
            int j = t & 15;
            const int offs[4] = {0, 16, 48, 112};
            double row[8];
            for (int s = 0; s < 8; ++s) row[s] = 0.0;
            double scale = (double)S / 16.0;
            double x = (j + 0.5) * scale - 0.5;
            double x0 = floor(x);
            double tt = x - x0;
            for (int k = 0; k < 4; ++k) {
                int idx = (int)x0 - 1 + k;
                idx = idx < 0 ? 0 : (idx > S - 1 ? S - 1 : idx);
                row[idx] += cubic_d(tt + 1.0 - k);
            }
            for (int s = 0; s < S; ++s) wmat[offs[sIdx] + j * S + s] = (float)row[s];
        }
        if (bid == 0 && t == 0) lossA[0] = 0.f;
        for (int i = bid * 256 + t; i < 8192; i += NB * 256) packed[i] = ~0ull;
    }
    grid.sync();

    const int Ss[5]     = {1, 2, 4, 8, 16};
    const int phiIdx[5] = {0, 1, 1, 2, 3};
    const int ksplit[5] = {256, 256, 128, 64, 16};
    const int wmOff[5]  = {0, 16, 48, 112, 0};
    const int pOff[5]   = {0, 16, 80, 336, 1360};
    const int padNs[5]  = {128, 128, 256, 1024, 4096};

    for (int si = 0; si < 5; ++si) {
        const int S = Ss[si];
        const int N = 16 * S * S;
        const int padN = padNs[si];
        const int KS = ksplit[si];
        u64* pk = packed + pOff[si];

        // ---- pack (si=0 in prologue; si=4 via packNext epilogue) ----
        if (si == 1) {
            const int w = t >> 6, lane = t & 63;
            for (int wj = bid * 4 + w; wj < padN * 128; wj += NB * 4) {
                int row = wj >> 7, c = wj & 127;
                float x = 0.f;
                if (row < N) {
                    int tt = row & 1, ssi = (row >> 1) & 1, b = row >> 2;
                    const float* basep = f_rest + (size_t)(b * 128 + c) * 256 + (ssi * 8) * 16 + tt * 8;
                    float acc = 0.f;
                    for (int e = lane; e < 64; e += 64)
                        acc += basep[(e >> 3) * 16 + (e & 7)];
                    #pragma unroll
                    for (int off = 32; off; off >>= 1) acc += __shfl_down(acc, off);
                    x = acc * (1.f / 64.f);
                }
                if (lane == 0) {
                    ushortT h = f2bf(x);
                    rext[(size_t)row * 256 + c] = h;
                    rext[(size_t)row * 256 + 128 + c] = f2bf(x - bf2f(h));
                }
            }
            grid.sync();
        } else if (si == 2 || si == 3) {
            const int lgS = si;
            for (int id2 = bid * 256 + t; id2 < padN * 32; id2 += NB * 256) {
                int row = id2 >> 5, c4 = id2 & 31;
                ushortT hi[4], lo[4];
                if (row < N) {
                    int mask = S - 1;
                    int tt = row & mask, ssi = (row >> lgS) & mask, b = row >> (2 * lgS);
                    int bs = 16 >> lgS;
                    float inv = 1.f / (float)(bs * bs);
                    #pragma unroll
                    for (int u = 0; u < 4; ++u) {
                        int c = c4 * 4 + u;
                        const float* basep = f_rest + (size_t)(b * 128 + c) * 256 + (ssi * bs) * 16 + tt * bs;
                        float acc = 0.f;
                        for (int jj = 0; jj < bs; ++jj)
                            for (int ll = 0; ll < bs; ++ll)
                                acc += basep[jj * 16 + ll];
                        float x = acc * inv;
                        hi[u] = f2bf(x);
                        lo[u] = f2bf(x - bf2f(hi[u]));
                    }
                } else {
                    #pragma unroll
                    for (int u = 0; u < 4; ++u) { hi[u] = 0; lo[u] = 0; }
                }
                ushortT* basep = rext + (size_t)row * 256;
                *reinterpret_cast<ushort4*>(basep + c4 * 4)       = make_ushort4(hi[0], hi[1], hi[2], hi[3]);
                *reinterpret_cast<ushort4*>(basep + 128 + c4 * 4) = make_ushort4(lo[0], lo[1], lo[2], lo[3]);
            }
            grid.sync();
        }

        // ---- argmin (job-strided; block-uniform loop) ----
        {
            int njobs = (padN / 128) * KS;
            for (int jid = bid; jid < njobs; jid += NB)
                dev_argmin_sb(smem, jid, rext, embext, esq, N, NCODE / KS, KS, pk, t);
            grid.sync();
        }

        // ---- upconv (job-strided) ----
        {
            int k = phiIdx[si];
            for (int job = bid; job < 256; job += NB)
                dev_upconv(smem, job, emb, pk, wmat + wmOff[si], S, si == 4 ? 1 : 0,
                           wext + (size_t)k * 147456, phi_b + (size_t)k * 128,
                           f, out, f_rest, lossA,
                           si <= 2 ? 1 : 0, si == 3 ? 1 : 0, rext, t);
            grid.sync();
        }
    }

    // ---------------- final ----------------
    if (bid == 0) {
        u32* cnt2 = reinterpret_cast<u32*>(smem);         // 32 KB exactly
        for (int i = t; i < NCODE / 2; i += 256) cnt2[i] = 0;
        __syncthreads();
        for (int i = t; i < NTOT; i += 256) {
            int idx = (int)(u32)(packed[i] & 0xFFFFFFFFull);
            atomicAdd(&cnt2[idx >> 1], (idx & 1) ? 65536u : 1u);
        }
        __syncthreads();
        float s = 0.f;
        for (int k = t; k < NCODE; k += 256) {
            u32 c = cnt2[k >> 1];
            c = (k & 1) ? (c >> 16) : (c & 0xFFFFu);
            float p = (float)c * (1.0f / (float)NTOT);
            s += p * logf(p + 1e-10f);
        }
        __syncthreads();                       // all reads of cnt2 done
        float* ws4 = reinterpret_cast<float*>(smem);
        #pragma unroll
        for (int off = 32; off; off >>= 1) s += __shfl_down(s, off);
        if ((t & 63) == 0) ws4[t >> 6] = s;
        __syncthreads();
        if (t == 0) {
            out[ELEMS]     = lossA[0];
            out[ELEMS + 1] = expf(-(ws4[0] + ws4[1] + ws4[2] + ws4[3]));
        }
    }
}

// ===========================================================================
// Fallback path: R11 kernels (measured 320.5 us) — used if cooperative
// launch is unavailable or fails.
// ===========================================================================
__global__ __launch_bounds__(256)
void k_prologue(const float* __restrict__ f, const float* __restrict__ emb,
                const float* __restrict__ phi_w,
                float* __restrict__ f_rest, float* __restrict__ f_hat,
                float* __restrict__ esq, ushortT* __restrict__ embext,
                ushortT* __restrict__ wext, float* __restrict__ wmat,
                float* __restrict__ lossA, ushortT* __restrict__ rext,
                u64* __restrict__ packed) {
    __shared__ float red[4];
    const int t = threadIdx.x;
    const int bid = blockIdx.x;
    const int id = bid * 256 + t;

    if (bid < 2048) {
        float fv = f[id];
        f_rest[id] = fv;
        f_hat[id] = 0.f;
        int row = id >> 5, c4 = id & 31;
        float4 v = reinterpret_cast<const float4*>(emb + (size_t)row * CDIM)[c4];
        float xs[4] = {v.x, v.y, v.z, v.w};
        ushortT hi[4], lo[4];
        float ss = 0.f;
        #pragma unroll
        for (int i = 0; i < 4; ++i) {
            hi[i] = f2bf(xs[i]);
            lo[i] = f2bf(xs[i] - bf2f(hi[i]));
            ss += xs[i] * xs[i];
        }
        ushortT* base = embext + (size_t)row * 256;
        *reinterpret_cast<ushort4*>(base + c4 * 4)       = make_ushort4(hi[0], hi[1], hi[2], hi[3]);
        *reinterpret_cast<ushort4*>(base + 128 + c4 * 4) = make_ushort4(lo[0], lo[1], lo[2], lo[3]);
        #pragma unroll
        for (int off = 16; off; off >>= 1) ss += __shfl_down(ss, off);
        if ((t & 31) == 0) esq[row] = ss;

        float s = fv;
        #pragma unroll
        for (int off = 32; off; off >>= 1) s += __shfl_down(s, off);
        if ((t & 63) == 0) red[t >> 6] = s;
        __syncthreads();
        if (t == 0) {
            float m = (red[0] + red[1] + red[2] + red[3]) * (1.f / 256.f);
            int b = bid >> 7, c = bid & 127;
            ushortT h = f2bf(m);
            rext[b * 256 + c] = h;
            rext[b * 256 + 128 + c] = f2bf(m - bf2f(h));
        }
    } else {
        int idz = (bid - 2048) * 256 + t;
        if (idz < 30720)
            reinterpret_cast<u32*>(rext + 16 * 256)[idz] = 0;
    }
    if (id < WEXT_TOT) {
        int k4 = id / 147456, rem = id % 147456;
        int co = rem / 1152, kk = rem % 1152;
        int off = kk >> 7, ci = kk & 127;
        float v = 0.5f * phi_w[(((size_t)(k4 * 128 + co)) * 128 + ci) * 9 + off];
        if (ci == co && off == 4) v += 0.5f;
        wext[id] = f2bf(v);
    }
    if (bid == 0 && t < 64) {
        int sIdx = t >> 4;
        int S = 1 << sIdx;
        int j = t & 15;
        const int offs[4] = {0, 16, 48, 112};
        double row[8];
        for (int s = 0; s < 8; ++s) row[s] = 0.0;
        double scale = (double)S / 16.0;
        double x = (j + 0.5) * scale - 0.5;
        double x0 = floor(x);
        double tt = x - x0;
        for (int k = 0; k < 4; ++k) {
            int idx = (int)x0 - 1 + k;
            idx = idx < 0 ? 0 : (idx > S - 1 ? S - 1 : idx);
            row[idx] += cubic_d(tt + 1.0 - k);
        }
        for (int s = 0; s < S; ++s) wmat[offs[sIdx] + j * S + s] = (float)row[s];
    }
    if (id == 0) lossA[0] = 0.f;
    if (id < 8192) packed[id] = ~0ull;
}

__global__ __launch_bounds__(256)
void k_packext(const float* __restrict__ fr, ushortT* __restrict__ re,
               int N, int padN, int S, int lgS) {
    int id = blockIdx.x * 256 + threadIdx.x;
    if (id >= padN * 32) return;
    int row = id >> 5, c4 = id & 31;
    ushortT hi[4], lo[4];
    if (row < N) {
        int mask = S - 1;
        int tt = row & mask, ssi = (row >> lgS) & mask, b = row >> (2 * lgS);
        int bs = 16 >> lgS;
        float inv = 1.f / (float)(bs * bs);
        #pragma unroll
        for (int u = 0; u < 4; ++u) {
            int c = c4 * 4 + u;
            const float* base = fr + (size_t)(b * 128 + c) * 256 + (ssi * bs) * 16 + tt * bs;
            float acc = 0.f;
            for (int jj = 0; jj < bs; ++jj)
                for (int ll = 0; ll < bs; ++ll)
                    acc += base[jj * 16 + ll];
            float x = acc * inv;
            hi[u] = f2bf(x);
            lo[u] = f2bf(x - bf2f(hi[u]));
        }
    } else {
        #pragma unroll
        for (int u = 0; u < 4; ++u) { hi[u] = 0; lo[u] = 0; }
    }
    ushortT* base = re + (size_t)row * 256;
    *reinterpret_cast<ushort4*>(base + c4 * 4)       = make_ushort4(hi[0], hi[1], hi[2], hi[3]);
    *reinterpret_cast<ushort4*>(base + 128 + c4 * 4) = make_ushort4(lo[0], lo[1], lo[2], lo[3]);
}

__global__ __launch_bounds__(256)
void k_packext_wave(const float* __restrict__ fr, ushortT* __restrict__ re,
                    int N, int padN, int S, int lgS) {
    int gid = blockIdx.x * 256 + threadIdx.x;
    int wid = gid >> 6, lane = threadIdx.x & 63;
    if (wid >= padN * 128) return;
    int row = wid >> 7, c = wid & 127;
    float x = 0.f;
    if (row < N) {
        int mask = S - 1;
        int tt = row & mask, ssi = (row >> lgS) & mask, b = row >> (2 * lgS);
        int lgbs = 4 - lgS, bs = 1 << lgbs, cnt = bs * bs;
        const float* base = fr + (size_t)(b * 128 + c) * 256 + (ssi * bs) * 16 + tt * bs;
        float acc = 0.f;
        for (int e = lane; e < cnt; e += 64)
            acc += base[(e >> lgbs) * 16 + (e & (bs - 1))];
        #pragma unroll
        for (int off = 32; off; off >>= 1) acc += __shfl_down(acc, off);
        x = acc / (float)cnt;
    }
    if (lane == 0) {
        ushortT h = f2bf(x);
        re[(size_t)row * 256 + c] = h;
        re[(size_t)row * 256 + 128 + c] = f2bf(x - bf2f(h));
    }
}

__global__ __launch_bounds__(256)
void k_argmin_fb(const ushortT* __restrict__ rext, const ushortT* __restrict__ embext,
                 const float* __restrict__ esq, int N, int kPerSplit, int KS,
                 u64* __restrict__ packed) {
    __shared__ __align__(16) char smem[32768];
    dev_argmin_sb(smem, blockIdx.x, rext, embext, esq, N, kPerSplit, KS, packed,
                  threadIdx.x);
}

__global__ __launch_bounds__(256)
void k_upconv_fb(const float* __restrict__ emb, const u64* __restrict__ packed,
                 const float* __restrict__ wm, int S, int lastScale,
                 const ushortT* __restrict__ wext, const float* __restrict__ bias,
                 const float* __restrict__ f_in, float* __restrict__ f_hat,
                 float* __restrict__ f_rest, float* __restrict__ loss_acc,
                 int storeRest, int packNext, ushortT* __restrict__ rext_out) {
    __shared__ __align__(16) char smem[24592];
    dev_upconv(smem, blockIdx.x, emb, packed, wm, S, lastScale, wext, bias,
               f_in, f_hat, f_rest, loss_acc, storeRest, packNext, rext_out,
               threadIdx.x);
}

__global__ __launch_bounds__(256)
void k_final(const u64* __restrict__ packed, const float* __restrict__ loss_acc,
             float* __restrict__ out) {
    __shared__ u32 cnt2[NCODE / 2];
    __shared__ float ws4[4];
    int t = threadIdx.x;
    for (int i = t; i < NCODE / 2; i += 256) cnt2[i] = 0;
    __syncthreads();
    for (int i = t; i < NTOT; i += 256) {
        int idx = (int)(u32)(packed[i] & 0xFFFFFFFFull);
        atomicAdd(&cnt2[idx >> 1], (idx & 1) ? 65536u : 1u);
    }
    __syncthreads();
    float s = 0.f;
    for (int k = t; k < NCODE; k += 256) {
        u32 c = cnt2[k >> 1];
        c = (k & 1) ? (c >> 16) : (c & 0xFFFFu);
        float p = (float)c * (1.0f / (float)NTOT);
        s += p * logf(p + 1e-10f);
    }
    #pragma unroll
    for (int off = 32; off; off >>= 1) s += __shfl_down(s, off);
    if ((t & 63) == 0) ws4[t >> 6] = s;
    __syncthreads();
    if (t == 0) {
        out[ELEMS]     = loss_acc[0];
        out[ELEMS + 1] = expf(-(ws4[0] + ws4[1] + ws4[2] + ws4[3]));
    }
}

// ---------------------------------------------------------------------------
extern "C" void kernel_launch(void* const* d_in, const int* in_sizes, int n_in,
                              void* d_out, int out_size, void* d_ws, size_t ws_size,
                              hipStream_t stream) {
    const float* f     = (const float*)d_in[0];
    const float* emb   = (const float*)d_in[1];
    const float* phi_w = (const float*)d_in[2];
    const float* phi_b = (const float*)d_in[3];
    float* out = (float*)d_out;

    float* wsf = (float*)d_ws;
    float*   f_rest = wsf;                        // 524288
    float*   esq    = wsf + 524288;               // 16384
    float*   wmat   = wsf + 540672;               // 256
    float*   lossA  = wsf + 540928;               // 64
    u64*     packed = (u64*)(wsf + 540992);       // 8192 u64
    ushortT* embext = (ushortT*)(wsf + 557376);   // 4194304 us
    ushortT* rext   = (ushortT*)(wsf + 2654528);  // 1048576 us
    ushortT* wext   = (ushortT*)(wsf + 3178816);  // 589824 us

    // Deterministic launch-config decision (pure queries; capture-safe).
    int coop = 0, dev = 0, nbPerCU = 0;
    hipError_t e0 = hipGetDevice(&dev);
    hipError_t e1 = hipDeviceGetAttribute(&coop, hipDeviceAttributeCooperativeLaunch, dev);
    hipError_t qerr = hipOccupancyMaxActiveBlocksPerMultiprocessor(
        &nbPerCU, k_mega, 256, 0);
    int gridN = nbPerCU * 256;
    if (gridN > 512) gridN = 512;

    hipError_t lerr = hipErrorUnknown;
    if (e0 == hipSuccess && e1 == hipSuccess && coop &&
        qerr == hipSuccess && gridN >= 128) {
        void* args[] = {
            (void*)&f, (void*)&emb, (void*)&phi_w, (void*)&phi_b, (void*)&out,
            (void*)&f_rest, (void*)&esq, (void*)&wmat, (void*)&lossA,
            (void*)&packed, (void*)&embext, (void*)&rext, (void*)&wext
        };
        lerr = hipLaunchCooperativeKernel((const void*)k_mega, dim3(gridN),
                                          dim3(256), args, 0, stream);
    }
    if (lerr != hipSuccess) {
        // ---- R11 fallback sequence (measured 320.5 us) ----
        k_prologue<<<2304, 256, 0, stream>>>(f, emb, phi_w, f_rest, out, esq,
                                             embext, wext, wmat, lossA, rext, packed);
        const int Ss[5]     = {1, 2, 4, 8, 16};
        const int lgSs[5]   = {0, 1, 2, 3, 4};
        const int phiIdx[5] = {0, 1, 1, 2, 3};
        const int ksplit[5] = {256, 256, 128, 64, 16};
        const int wmOff[5]  = {0, 16, 48, 112, 0};
        const int pOff[5]   = {0, 16, 80, 336, 1360};
        for (int si = 0; si < 5; ++si) {
            int S = Ss[si], lgS = lgSs[si];
            int N = 16 * S * S;
            int padN = (N + 127) & ~127;
            u64* pk = packed + pOff[si];
            if (si == 1)
                k_packext_wave<<<padN * 128 / 4, 256, 0, stream>>>(f_rest, rext, N, padN, S, lgS);
            else if (si == 2 || si == 3)
                k_packext<<<padN * 32 / 256, 256, 0, stream>>>(f_rest, rext, N, padN, S, lgS);
            int KS = ksplit[si];
            k_argmin_fb<<<(padN / 128) * KS, 256, 0, stream>>>(rext, embext, esq,
                                                               N, NCODE / KS, KS, pk);
            int k = phiIdx[si];
            k_upconv_fb<<<256, 256, 0, stream>>>(emb, pk, wmat + wmOff[si], S,
                                                 si == 4 ? 1 : 0,
                                                 wext + (size_t)k * 147456,
                                                 phi_b + (size_t)k * 128, f, out,
                                                 f_rest, lossA,
                                                 si <= 2 ? 1 : 0, si == 3 ? 1 : 0, rext);
        }
        k_final<<<1, 256, 0, stream>>>(packed, lossA, out);
    }
}

// Round 16
// 319.941 us; speedup vs baseline: 2.1152x; 2.1152x over previous
//
#include <hip/hip_runtime.h>
#include <hip/hip_bf16.h>
#include <math.h>

// Problem constants
#define BATCH 16
#define CDIM  128
#define NCODE 16384
#define ELEMS 524288         // B*C*J*L
#define NTOT  5456           // 16+64+256+1024+4096
#define WEXT_TOT 589824      // 4*128*1152
// loss coeff: 1.25 / (5 * 524288) == 2^-21
#define LOSS_COEF 4.76837158203125e-7f

typedef __attribute__((ext_vector_type(8))) short short8;
typedef __attribute__((ext_vector_type(4))) float float4v;
typedef unsigned short ushortT;
typedef unsigned long long u64;
typedef unsigned int u32;

__device__ __forceinline__ ushortT f2bf(float x) {
    __hip_bfloat16 h = __float2bfloat16(x);
    return *reinterpret_cast<ushortT*>(&h);
}
__device__ __forceinline__ float bf2f(ushortT b) {
    __hip_bfloat16 h = *reinterpret_cast<__hip_bfloat16*>(&b);
    return __bfloat162float(h);
}
// monotone float -> uint mapping (for lexicographic u64 atomicMin)
__device__ __forceinline__ u32 ford(float v) {
    u32 b = __float_as_uint(v);
    return b ^ ((u32)((int)b >> 31) | 0x80000000u);
}

// ---------------------------------------------------------------------------
// bicubic kernel (align_corners=False, a=-0.75), double math
__device__ double cubic_d(double x) {
    const double a = -0.75;
    double ax = fabs(x);
    if (ax <= 1.0) return (a + 2.0) * ax * ax * ax - (a + 3.0) * ax * ax + 1.0;
    if (ax < 2.0)  return a * ax * ax * ax - 5.0 * a * ax * ax + 8.0 * a * ax - 4.0 * a;
    return 0.0;
}

// ---------------------------------------------------------------------------
// prologue: f_rest=f, f_hat=0, esq, embext(split-bf16), wext, wmat, loss=0,
//           ALL packed slabs init, scale-0 pack (plane mean), rext pad rows zero
__global__ __launch_bounds__(256)
void k_prologue(const float* __restrict__ f, const float* __restrict__ emb,
                const float* __restrict__ phi_w,
                float* __restrict__ f_rest, float* __restrict__ f_hat,
                float* __restrict__ esq, ushortT* __restrict__ embext,
                ushortT* __restrict__ wext, float* __restrict__ wmat,
                float* __restrict__ lossA, ushortT* __restrict__ rext,
                u64* __restrict__ packed) {
    __shared__ float red[4];
    const int t = threadIdx.x;
    const int bid = blockIdx.x;
    const int id = bid * 256 + t;

    if (bid < 2048) {
        float fv = f[id];
        f_rest[id] = fv;
        f_hat[id] = 0.f;
        int row = id >> 5, c4 = id & 31;
        float4 v = reinterpret_cast<const float4*>(emb + (size_t)row * CDIM)[c4];
        float xs[4] = {v.x, v.y, v.z, v.w};
        ushortT hi[4], lo[4];
        float ss = 0.f;
        #pragma unroll
        for (int i = 0; i < 4; ++i) {
            hi[i] = f2bf(xs[i]);
            lo[i] = f2bf(xs[i] - bf2f(hi[i]));
            ss += xs[i] * xs[i];
        }
        ushortT* base = embext + (size_t)row * 256;
        *reinterpret_cast<ushort4*>(base + c4 * 4)       = make_ushort4(hi[0], hi[1], hi[2], hi[3]);
        *reinterpret_cast<ushort4*>(base + 128 + c4 * 4) = make_ushort4(lo[0], lo[1], lo[2], lo[3]);
        #pragma unroll
        for (int off = 16; off; off >>= 1) ss += __shfl_down(ss, off);
        if ((t & 31) == 0) esq[row] = ss;

        // scale-0 pack: mean over the (b,c) plane (block == one plane)
        float s = fv;
        #pragma unroll
        for (int off = 32; off; off >>= 1) s += __shfl_down(s, off);
        if ((t & 63) == 0) red[t >> 6] = s;
        __syncthreads();
        if (t == 0) {
            float m = (red[0] + red[1] + red[2] + red[3]) * (1.f / 256.f);
            int b = bid >> 7, c = bid & 127;
            ushortT h = f2bf(m);
            rext[b * 256 + c] = h;
            rext[b * 256 + 128 + c] = f2bf(m - bf2f(h));
        }
    } else {
        // zero rext rows 16..255 (pad rows for small-scale argmin tiles)
        int idz = (bid - 2048) * 256 + t;
        if (idz < 30720)
            reinterpret_cast<u32*>(rext + 16 * 256)[idz] = 0;
    }
    if (id < WEXT_TOT) {
        int k4 = id / 147456, rem = id % 147456;
        int co = rem / 1152, kk = rem % 1152;
        int off = kk >> 7, ci = kk & 127;
        float v = 0.5f * phi_w[(((size_t)(k4 * 128 + co)) * 128 + ci) * 9 + off];
        if (ci == co && off == 4) v += 0.5f;
        wext[id] = f2bf(v);
    }
    if (bid == 0 && t < 64) {
        int sIdx = t >> 4;            // S = 1,2,4,8
        int S = 1 << sIdx;
        int j = t & 15;
        const int offs[4] = {0, 16, 48, 112};
        double row[8];
        for (int s = 0; s < 8; ++s) row[s] = 0.0;
        double scale = (double)S / 16.0;
        double x = (j + 0.5) * scale - 0.5;
        double x0 = floor(x);
        double tt = x - x0;
        for (int k = 0; k < 4; ++k) {
            int idx = (int)x0 - 1 + k;
            idx = idx < 0 ? 0 : (idx > S - 1 ? S - 1 : idx);
            row[idx] += cubic_d(tt + 1.0 - k);
        }
        for (int s = 0; s < S; ++s) wmat[offs[sIdx] + j * S + s] = (float)row[s];
    }
    if (id == 0) lossA[0] = 0.f;
    if (id < 8192) packed[id] = ~0ull;
}

// ---------------------------------------------------------------------------
// fused pack+rext (S>=4): thread per (row, c4)
__global__ __launch_bounds__(256)
void k_packext(const float* __restrict__ fr, ushortT* __restrict__ re,
               int N, int padN, int S, int lgS) {
    int id = blockIdx.x * 256 + threadIdx.x;
    if (id >= padN * 32) return;
    int row = id >> 5, c4 = id & 31;
    ushortT hi[4], lo[4];
    if (row < N) {
        int mask = S - 1;
        int tt = row & mask, ssi = (row >> lgS) & mask, b = row >> (2 * lgS);
        int bs = 16 >> lgS;
        float inv = 1.f / (float)(bs * bs);
        #pragma unroll
        for (int u = 0; u < 4; ++u) {
            int c = c4 * 4 + u;
            const float* base = fr + (size_t)(b * 128 + c) * 256 + (ssi * bs) * 16 + tt * bs;
            float acc = 0.f;
            for (int jj = 0; jj < bs; ++jj)
                for (int ll = 0; ll < bs; ++ll)
                    acc += base[jj * 16 + ll];
            float x = acc * inv;
            hi[u] = f2bf(x);
            lo[u] = f2bf(x - bf2f(hi[u]));
        }
    } else {
        #pragma unroll
        for (int u = 0; u < 4; ++u) { hi[u] = 0; lo[u] = 0; }
    }
    ushortT* base = re + (size_t)row * 256;
    *reinterpret_cast<ushort4*>(base + c4 * 4)       = make_ushort4(hi[0], hi[1], hi[2], hi[3]);
    *reinterpret_cast<ushort4*>(base + 128 + c4 * 4) = make_ushort4(lo[0], lo[1], lo[2], lo[3]);
}

// wave-per-(row,channel) variant for S<=2 (big windows)
__global__ __launch_bounds__(256)
void k_packext_wave(const float* __restrict__ fr, ushortT* __restrict__ re,
                    int N, int padN, int S, int lgS) {
    int gid = blockIdx.x * 256 + threadIdx.x;
    int wid = gid >> 6, lane = threadIdx.x & 63;
    if (wid >= padN * 128) return;
    int row = wid >> 7, c = wid & 127;
    float x = 0.f;
    if (row < N) {
        int mask = S - 1;
        int tt = row & mask, ssi = (row >> lgS) & mask, b = row >> (2 * lgS);
        int lgbs = 4 - lgS, bs = 1 << lgbs, cnt = bs * bs;
        const float* base = fr + (size_t)(b * 128 + c) * 256 + (ssi * bs) * 16 + tt * bs;
        float acc = 0.f;
        for (int e = lane; e < cnt; e += 64)
            acc += base[(e >> lgbs) * 16 + (e & (bs - 1))];
        #pragma unroll
        for (int off = 32; off; off >>= 1) acc += __shfl_down(acc, off);
        x = acc / (float)cnt;
    }
    if (lane == 0) {
        ushortT h = f2bf(x);
        re[(size_t)row * 256 + c] = h;
        re[(size_t)row * 256 + 128 + c] = f2bf(x - bf2f(h));
    }
}

// ---------------------------------------------------------------------------
// MFMA argmin, split-bf16 3-term; TI=2 (M=128/block), dbuf B tile, one
// barrier/tile; per-row u64 atomicMin. 1-D grid, ky = id % KS so all blocks
// sharing a k-slice land on the same XCD (id%8 fixed) -> embext stays L2-hot.
// NOTE: TI=4 variants tested R6/R7/R9 all lose (occupancy/remat/spill);
// TC=32 tested R12 loses (more barriers, no occupancy gain);
// cooperative mega-kernel tested R15 loses 2x (grid.sync ~tens of us).
__global__ __launch_bounds__(256)
void k_argmin_mfma(const ushortT* __restrict__ rext, const ushortT* __restrict__ embext,
                   const float* __restrict__ esq, int N, int kPerSplit, int KS,
                   u64* __restrict__ packed) {
    __shared__ ushortT Btile[2][64 * 32 * 8];     // 2 x 32 KB
    const int t = threadIdx.x;
    const int w = t >> 6;
    const int lane = t & 63;
    const int ln = lane & 15;
    const int q  = lane >> 4;
    const int bid = blockIdx.x;
    const int ky = bid % KS;
    const int rb = bid / KS;
    const int k0beg = ky * kPerSplit;
    const int rowW = rb * 128 + w * 32;

    short8 a[2][8];
    #pragma unroll
    for (int ti = 0; ti < 2; ++ti) {
        const ushortT* r0 = rext + (size_t)(rowW + ti * 16 + ln) * 256 + q * 8;
        #pragma unroll
        for (int sb = 0; sb < 8; ++sb)
            a[ti][sb] = *reinterpret_cast<const short8*>(r0 + sb * 32);
    }

    float minv[2][4];
    int   mini[2][4];
    #pragma unroll
    for (int ti = 0; ti < 2; ++ti)
        #pragma unroll
        for (int rg = 0; rg < 4; ++rg) { minv[ti][rg] = 3.4e38f; mini[ti][rg] = 0; }

    const int tiles = kPerSplit >> 6;

    #pragma unroll
    for (int i = 0; i < 8; ++i) {
        int F = (i * 4 + w) * 64 + lane;
        int n = F >> 5, cs = F & 31;
        int cp = (cs & ~7) | ((cs & 7) ^ (n & 7));
        const ushortT* src = embext + (size_t)(k0beg + n) * 256 + cp * 8;
        __builtin_amdgcn_global_load_lds(
            (const __attribute__((address_space(1))) unsigned int*)src,
            (__attribute__((address_space(3))) unsigned int*)&Btile[0][(size_t)((i * 4 + w) * 64) * 8],
            16, 0, 0);
    }

    for (int it = 0; it < tiles; ++it) {
        __syncthreads();
        if (it + 1 < tiles) {
            int k1 = k0beg + (it + 1) * 64;
            int bu = (it + 1) & 1;
            #pragma unroll
            for (int i = 0; i < 8; ++i) {
                int F = (i * 4 + w) * 64 + lane;
                int n = F >> 5, cs = F & 31;
                int cp = (cs & ~7) | ((cs & 7) ^ (n & 7));
                const ushortT* src = embext + (size_t)(k1 + n) * 256 + cp * 8;
                __builtin_amdgcn_global_load_lds(
                    (const __attribute__((address_space(1))) unsigned int*)src,
                    (__attribute__((address_space(3))) unsigned int*)&Btile[bu][(size_t)((i * 4 + w) * 64) * 8],
                    16, 0, 0);
            }
        }
        const ushortT* Bt = Btile[it & 1];
        const int k0 = k0beg + it * 64;

        #pragma unroll
        for (int sub = 0; sub < 4; ++sub) {
            int n = sub * 16 + ln;
            short8 bfr[8];
            #pragma unroll
            for (int sb = 0; sb < 8; ++sb) {
                int cp = q + 4 * sb;
                int cs = (cp & ~7) | ((cp & 7) ^ (n & 7));
                bfr[sb] = *reinterpret_cast<const short8*>(&Bt[(size_t)(n * 32 + cs) * 8]);
            }
            float4v acc[2];
            #pragma unroll
            for (int ti = 0; ti < 2; ++ti) acc[ti] = (float4v){0.f, 0.f, 0.f, 0.f};
            #pragma unroll
            for (int s = 0; s < 12; ++s) {
                int as = s < 8 ? s : s - 8;
                int bs = s < 4 ? s : s - 4;
                #pragma unroll
                for (int ti = 0; ti < 2; ++ti)
                    acc[ti] = __builtin_amdgcn_mfma_f32_16x16x32_bf16(a[ti][as], bfr[bs], acc[ti], 0, 0, 0);
            }
            int kc = k0 + sub * 16 + ln;
            float es = esq[kc];
            #pragma unroll
            for (int ti = 0; ti < 2; ++ti)
                #pragma unroll
                for (int rg = 0; rg < 4; ++rg) {
                    float sc = fmaf(-2.f, acc[ti][rg], es);
                    if (sc < minv[ti][rg]) { minv[ti][rg] = sc; mini[ti][rg] = kc; }
                }
        }
    }

    #pragma unroll
    for (int ti = 0; ti < 2; ++ti)
        #pragma unroll
        for (int rg = 0; rg < 4; ++rg) {
            float v = minv[ti][rg]; int ix = mini[ti][rg];
            #pragma unroll
            for (int off = 1; off < 16; off <<= 1) {
                float ov = __shfl_xor(v, off);
                int   oi = __shfl_xor(ix, off);
                if (ov < v || (ov == v && oi < ix)) { v = ov; ix = oi; }
            }
            if (ln == 0) {
                int row = rowW + ti * 16 + q * 4 + rg;
                if (row < N) {
                    u64 p = ((u64)ford(v) << 32) | (u32)ix;
                    atomicMin(&packed[row], p);
                }
            }
        }
}

// ---------------------------------------------------------------------------
// Fused upsample/gather + MFMA conv3x3 (folded residual) + f_hat/f_rest/loss.
// grid = (b,j) = 256 blocks. Separable bicubic. Epilogue options:
//   storeRest : write updated f_rest (needed while later packs read it)
//   packNext  : write NEXT scale's rext directly (scale-4 pack == identity)
__global__ __launch_bounds__(256)
void k_upconv(const float* __restrict__ emb, const u64* __restrict__ packed,
              const float* __restrict__ wm, int S, int lastScale,
              const ushortT* __restrict__ wext, const float* __restrict__ bias,
              const float* __restrict__ f_in, float* __restrict__ f_hat,
              float* __restrict__ f_rest, float* __restrict__ loss_acc,
              int storeRest, int packNext, ushortT* __restrict__ rext_out) {
    __shared__ __align__(16) ushortT Htile[3 * 16 * 128];   // 12 KB
    __shared__ __align__(16) float tmpS[3 * 8 * 128];       // 12 KB (S<=8)
    __shared__ float wsum[4];
    const int t = threadIdx.x;
    const int b = blockIdx.x >> 4;
    const int j = blockIdx.x & 15;
    const int l = t >> 4, c8 = t & 15;
    const int phys = (c8 & 8) | ((c8 & 7) ^ (l & 7));

    if (lastScale) {
        #pragma unroll
        for (int r = 0; r < 3; ++r) {
            int jin = j - 1 + r;
            float acc[8] = {0.f, 0.f, 0.f, 0.f, 0.f, 0.f, 0.f, 0.f};
            if (jin >= 0 && jin < 16) {
                int idx = (int)(u32)(packed[(b * 16 + jin) * 16 + l] & 0xFFFFFFFFull);
                const float* er = emb + (size_t)idx * CDIM + c8 * 8;
                float4 e0 = *reinterpret_cast<const float4*>(er);
                float4 e1 = *reinterpret_cast<const float4*>(er + 4);
                acc[0] = e0.x; acc[1] = e0.y; acc[2] = e0.z; acc[3] = e0.w;
                acc[4] = e1.x; acc[5] = e1.y; acc[6] = e1.z; acc[7] = e1.w;
            }
            short8 o;
            #pragma unroll
            for (int i = 0; i < 8; ++i) o[i] = (short)f2bf(acc[i]);
            *reinterpret_cast<short8*>(&Htile[((size_t)(r * 16 + l) * 16 + phys) * 8]) = o;
        }
    } else {
        // stage 1: tmp[r][t2][c] = sum_s wm[jin*S+s] * E[s*S+t2][c]
        int items = 3 * S * 16;
        for (int i = t; i < items; i += 256) {
            int r = i / (S * 16);
            int rem = i - r * (S * 16);
            int t2 = rem >> 4, cc8 = rem & 15;
            int jin = j - 1 + r;
            float a0[8] = {0.f, 0.f, 0.f, 0.f, 0.f, 0.f, 0.f, 0.f};
            if (jin >= 0 && jin < 16) {
                for (int s = 0; s < S; ++s) {
                    float wjv = wm[jin * S + s];
                    int idx = (int)(u32)(packed[b * S * S + s * S + t2] & 0xFFFFFFFFull);
                    const float* er = emb + (size_t)idx * CDIM + cc8 * 8;
                    float4 e0 = *reinterpret_cast<const float4*>(er);
                    float4 e1 = *reinterpret_cast<const float4*>(er + 4);
                    a0[0] += wjv * e0.x; a0[1] += wjv * e0.y;
                    a0[2] += wjv * e0.z; a0[3] += wjv * e0.w;
                    a0[4] += wjv * e1.x; a0[5] += wjv * e1.y;
                    a0[6] += wjv * e1.z; a0[7] += wjv * e1.w;
                }
            }
            float* tp = &tmpS[((size_t)(r * 8 + t2)) * 128 + cc8 * 8];
            *reinterpret_cast<float4*>(tp)     = make_float4(a0[0], a0[1], a0[2], a0[3]);
            *reinterpret_cast<float4*>(tp + 4) = make_float4(a0[4], a0[5], a0[6], a0[7]);
        }
        __syncthreads();
        // stage 2: h[r][l][c] = sum_t2 wm[l*S+t2] * tmp[r][t2][c]
        #pragma unroll
        for (int r = 0; r < 3; ++r) {
            float acc[8] = {0.f, 0.f, 0.f, 0.f, 0.f, 0.f, 0.f, 0.f};
            for (int t2 = 0; t2 < S; ++t2) {
                float wlv = wm[l * S + t2];
                const float* tp = &tmpS[((size_t)(r * 8 + t2)) * 128 + c8 * 8];
                float4 v0 = *reinterpret_cast<const float4*>(tp);
                float4 v1 = *reinterpret_cast<const float4*>(tp + 4);
                acc[0] += wlv * v0.x; acc[1] += wlv * v0.y;
                acc[2] += wlv * v0.z; acc[3] += wlv * v0.w;
                acc[4] += wlv * v1.x; acc[5] += wlv * v1.y;
                acc[6] += wlv * v1.z; acc[7] += wlv * v1.w;
            }
            short8 o;
            #pragma unroll
            for (int i = 0; i < 8; ++i) o[i] = (short)f2bf(acc[i]);
            *reinterpret_cast<short8*>(&Htile[((size_t)(r * 16 + l) * 16 + phys) * 8]) = o;
        }
    }
    __syncthreads();

    // ---- conv phase ----
    const int w = t >> 6, lane = t & 63;
    const int ln = lane & 15, q = lane >> 4;
    const int co0 = w * 32;
    const ushortT* wA = wext + (size_t)(co0 + ln) * 1152;
    float4v acc2[2] = {{0.f, 0.f, 0.f, 0.f}, {0.f, 0.f, 0.f, 0.f}};
    const short8 zz = {0, 0, 0, 0, 0, 0, 0, 0};

    #pragma unroll 3
    for (int off = 0; off < 9; ++off) {
        const int dj = off / 3, dl = off % 3;
        int cIn = ln + dl - 1;
        int cCl = cIn < 0 ? 0 : (cIn > 15 ? 15 : cIn);
        bool oob = (cIn != cCl);
        int rb = (dj * 16 + cCl) * 128;
        #pragma unroll
        for (int g = 0; g < 4; ++g) {
            int csl = g * 4 + q;
            int ph2 = (csl & 8) | ((csl & 7) ^ (cCl & 7));
            short8 av = *reinterpret_cast<const short8*>(&Htile[rb + ph2 * 8]);
            if (oob) av = zz;
            const ushortT* wr = wA + (off * 4 + g) * 32 + q * 8;
            short8 b0 = *reinterpret_cast<const short8*>(wr);
            short8 b1 = *reinterpret_cast<const short8*>(wr + 16 * 1152);
            acc2[0] = __builtin_amdgcn_mfma_f32_16x16x32_bf16(av, b0, acc2[0], 0, 0, 0);
            acc2[1] = __builtin_amdgcn_mfma_f32_16x16x32_bf16(av, b1, acc2[1], 0, 0, 0);
        }
    }

    float s = 0.f;
    #pragma unroll
    for (int sn = 0; sn < 2; ++sn) {
        int co = co0 + sn * 16 + ln;
        float bsv = 0.5f * bias[co];
        size_t gi = ((size_t)(b * 128 + co) * 16 + j) * 16 + q * 4;
        float4 fh = *reinterpret_cast<const float4*>(&f_hat[gi]);
        float4 fv = *reinterpret_cast<const float4*>(&f_in[gi]);
        float oo[4] = {acc2[sn][0] + bsv, acc2[sn][1] + bsv,
                       acc2[sn][2] + bsv, acc2[sn][3] + bsv};
        float fhv[4] = {fh.x + oo[0], fh.y + oo[1], fh.z + oo[2], fh.w + oo[3]};
        *reinterpret_cast<float4*>(&f_hat[gi]) =
            make_float4(fhv[0], fhv[1], fhv[2], fhv[3]);
        float fvv[4] = {fv.x, fv.y, fv.z, fv.w};
        #pragma unroll
        for (int i = 0; i < 4; ++i) {
            float d = fhv[i] - fvv[i];
            s += d * d;
        }
        if (storeRest || packNext) {
            float4 fr = *reinterpret_cast<const float4*>(&f_rest[gi]);
            float frn[4] = {fr.x - oo[0], fr.y - oo[1], fr.z - oo[2], fr.w - oo[3]};
            if (storeRest)
                *reinterpret_cast<float4*>(&f_rest[gi]) =
                    make_float4(frn[0], frn[1], frn[2], frn[3]);
            if (packNext) {
                // next-scale rext rows: row = b*256 + j*16 + l, c = co
                #pragma unroll
                for (int i = 0; i < 4; ++i) {
                    int row = b * 256 + j * 16 + q * 4 + i;
                    ushortT hv = f2bf(frn[i]);
                    rext_out[(size_t)row * 256 + co] = hv;
                    rext_out[(size_t)row * 256 + 128 + co] = f2bf(frn[i] - bf2f(hv));
                }
            }
        }
    }
    #pragma unroll
    for (int off = 32; off; off >>= 1) s += __shfl_down(s, off);
    if (lane == 0) wsum[w] = s;
    __syncthreads();
    if (t == 0)
        atomicAdd(loss_acc, (wsum[0] + wsum[1] + wsum[2] + wsum[3]) * LOSS_COEF);
}

// ---------------------------------------------------------------------------
// fused histogram + perplexity + loss write (single block, LDS u16-pair counts)
__global__ __launch_bounds__(256)
void k_final(const u64* __restrict__ packed, const float* __restrict__ loss_acc,
             float* __restrict__ out) {
    __shared__ u32 cnt2[NCODE / 2];     // 32 KB
    __shared__ float ws4[4];
    int t = threadIdx.x;
    for (int i = t; i < NCODE / 2; i += 256) cnt2[i] = 0;
    __syncthreads();
    for (int i = t; i < NTOT; i += 256) {
        int idx = (int)(u32)(packed[i] & 0xFFFFFFFFull);
        atomicAdd(&cnt2[idx >> 1], (idx & 1) ? 65536u : 1u);
    }
    __syncthreads();
    float s = 0.f;
    for (int k = t; k < NCODE; k += 256) {
        u32 c = cnt2[k >> 1];
        c = (k & 1) ? (c >> 16) : (c & 0xFFFFu);
        float p = (float)c * (1.0f / (float)NTOT);
        s += p * logf(p + 1e-10f);
    }
    #pragma unroll
    for (int off = 32; off; off >>= 1) s += __shfl_down(s, off);
    if ((t & 63) == 0) ws4[t >> 6] = s;
    __syncthreads();
    if (t == 0) {
        out[ELEMS]     = loss_acc[0];
        out[ELEMS + 1] = expf(-(ws4[0] + ws4[1] + ws4[2] + ws4[3]));
    }
}

// ---------------------------------------------------------------------------
extern "C" void kernel_launch(void* const* d_in, const int* in_sizes, int n_in,
                              void* d_out, int out_size, void* d_ws, size_t ws_size,
                              hipStream_t stream) {
    const float* f     = (const float*)d_in[0];
    const float* emb   = (const float*)d_in[1];
    const float* phi_w = (const float*)d_in[2];
    const float* phi_b = (const float*)d_in[3];
    float* out = (float*)d_out;

    float* wsf = (float*)d_ws;
    float*   f_rest = wsf;                        // 524288
    float*   esq    = wsf + 524288;               // 16384
    float*   wmat   = wsf + 540672;               // 256
    float*   lossA  = wsf + 540928;               // 64
    u64*     packed = (u64*)(wsf + 540992);       // 8192 u64 = 16384 f
    ushortT* embext = (ushortT*)(wsf + 557376);   // 4194304 us = 2097152 f
    ushortT* rext   = (ushortT*)(wsf + 2654528);  // 1048576 us = 524288 f
    ushortT* wext   = (ushortT*)(wsf + 3178816);  // 589824 us = 294912 f
    // total ~3.47M floats = 13.9 MB

    k_prologue<<<2304, 256, 0, stream>>>(f, emb, phi_w, f_rest, out, esq,
                                         embext, wext, wmat, lossA, rext, packed);

    const int Ss[5]     = {1, 2, 4, 8, 16};
    const int lgSs[5]   = {0, 1, 2, 3, 4};
    const int phiIdx[5] = {0, 1, 1, 2, 3};
    const int ksplit[5] = {256, 256, 128, 64, 16};   // measured-best (R5/R10/R11)
    const int wmOff[5]  = {0, 16, 48, 112, 0};
    const int pOff[5]   = {0, 16, 80, 336, 1360};

    for (int si = 0; si < 5; ++si) {
        int S = Ss[si], lgS = lgSs[si];
        int N = 16 * S * S;
        int padN = (N + 127) & ~127;
        u64* pk = packed + pOff[si];

        // pack (scale 0 in prologue; scale 4 written by upconv si=3 epilogue)
        if (si == 1)
            k_packext_wave<<<padN * 128 / 4, 256, 0, stream>>>(f_rest, rext, N, padN, S, lgS);
        else if (si == 2 || si == 3)
            k_packext<<<padN * 32 / 256, 256, 0, stream>>>(f_rest, rext, N, padN, S, lgS);

        int KS = ksplit[si];
        k_argmin_mfma<<<(padN / 128) * KS, 256, 0, stream>>>(rext, embext, esq,
                                                             N, NCODE / KS, KS, pk);

        int k = phiIdx[si];
        k_upconv<<<256, 256, 0, stream>>>(emb, pk, wmat + wmOff[si], S, si == 4 ? 1 : 0,
                                          wext + (size_t)k * 147456,
                                          phi_b + (size_t)k * 128, f, out, f_rest, lossA,
                                          si <= 2 ? 1 : 0, si == 3 ? 1 : 0, rext);
    }

    k_final<<<1, 256, 0, stream>>>(packed, lossA, out);
}